// Round 8
// baseline (549.715 us; speedup 1.0000x reference)
//
#include <hip/hip_runtime.h>

using u16 = unsigned short;
typedef float f32x4 __attribute__((ext_vector_type(4)));
typedef float f32x16 __attribute__((ext_vector_type(16)));
typedef __bf16 bf16x8 __attribute__((ext_vector_type(8)));
typedef u16 u16x8 __attribute__((ext_vector_type(8)));
typedef u16 u16x4 __attribute__((ext_vector_type(4)));

// dims: B=64, S=2048, ENC=1024, U=512, E=256, V=50000, IN=1280
// scratch layout (float units)
static constexpr int OF_HPB   = 262144;    // w1p: 512K u16 = 262144 floats
static constexpr int OF_CTXP  = 294912;    // hpb: 64*512
static constexpr int OF_STATS = 2392064;   // ctxp: 2048*1024
static constexpr int OF_XIN   = 2394112;   // stats: 2048
static constexpr int OF_ZPART = 2476032;   // xin: 64*1280
static constexpr int OF_HHL   = 3000320;   // zpart: 4*64*2048; hhl: 2*64*1024 u16
static constexpr size_t SCRATCH_FLOATS = 3065856;
static constexpr size_t SCRATCH_BYTES  = SCRATCH_FLOATS * 4ull;   // ~12.3 MB

__device__ __forceinline__ u16 f2bf(float f) {
  unsigned u = __float_as_uint(f);
  u += 0x7FFFu + ((u >> 16) & 1u);   // RNE; inputs finite
  return (u16)(u >> 16);
}
__device__ __forceinline__ float bf2f(u16 u) {
  return __uint_as_float((unsigned)u << 16);
}
__device__ __forceinline__ float fast_tanh(float x) {
  x = fminf(fmaxf(x, -20.f), 20.f);
  float e = __expf(2.f * x);
  return (e - 1.f) / (e + 1.f);
}
__device__ __forceinline__ float fast_sig(float x) { return 1.f / (1.f + __expf(-x)); }

// ---------------- W1 (1024x512 f32 [k][u]) -> bf16 packed for 32x32x16 B-frags:
// w1p[ks16*8192 + (wv*64 + l)*8 + e] = W1[ks16*16 + (l>>5)*8 + e][wv*32 + (l&31)]
// -> per wave per K-step one contiguous 1KB global read = its B fragment.
__global__ void k_prep_w1(const float* __restrict__ W1w, u16* __restrict__ w1p) {
  __shared__ float tile[16][516];
  const int t = threadIdx.x;          // 256
  const int ks = blockIdx.x;          // 64
  {
    int kk = t >> 4, u0 = (t & 15) * 32;
    const float* src = W1w + (size_t)(ks * 16 + kk) * 512 + u0;
    #pragma unroll
    for (int i = 0; i < 8; ++i)
      *(float4*)&tile[kk][u0 + i * 4] = *(const float4*)(src + i * 4);
  }
  __syncthreads();
  #pragma unroll
  for (int q = 0; q < 4; ++q) {
    int c = t + q * 256;              // chunk 0..1023
    int wv = c >> 6, l = c & 63;
    int u = wv * 32 + (l & 31), koct = l >> 5;
    u16x8 p;
    #pragma unroll
    for (int e = 0; e < 8; ++e) p[e] = f2bf(tile[koct * 8 + e][u]);
    *(u16x8*)(w1p + (size_t)ks * 8192 + (size_t)c * 8) = p;
  }
}

// ---------------- hpb[b][u] = c_fwd@W2 + W2_b + c_bwd@W3 + W3_b + W1_b
__global__ void k_prep_hp(const float* __restrict__ cf, const float* __restrict__ cb,
                          const float* __restrict__ W2w, const float* __restrict__ W2b,
                          const float* __restrict__ W3w, const float* __restrict__ W3b,
                          const float* __restrict__ W1b, float* __restrict__ hpb) {
  __shared__ float cfl[512], cbl[512];
  const int b = blockIdx.x, t = threadIdx.x;
  cfl[t] = cf[(size_t)b * 512 + t];       cfl[t + 256] = cf[(size_t)b * 512 + t + 256];
  cbl[t] = cb[(size_t)b * 512 + t];       cbl[t + 256] = cb[(size_t)b * 512 + t + 256];
  __syncthreads();
  const int u1 = t, u2 = t + 256;
  float a1 = W2b[u1] + W3b[u1] + W1b[u1];
  float a2 = W2b[u2] + W3b[u2] + W1b[u2];
  for (int k = 0; k < 512; ++k) {
    float c1 = cfl[k], c2 = cbl[k];
    const float* r2 = W2w + (size_t)k * 512;
    const float* r3 = W3w + (size_t)k * 512;
    a1 += c1 * r2[u1] + c2 * r3[u1];
    a2 += c1 * r2[u2] + c2 * r3[u2];
  }
  hpb[(size_t)b * 512 + u1] = a1;
  hpb[(size_t)b * 512 + u2] = a2;
}

// ---------------- fused attention v3: score GEMM (32x32x16 MFMA, BK=16) ->
// exp/stats -> tail-PV. 2048 blocks = 64 b x 32 tiles (64 rows). 1024 thr =
// 16 waves; wave wv owns u-cols wv*32..+32 (acc 2x f32x16 = 32 VGPR).
// B: DIRECT global->reg (1KB coalesced per wave per step, L2-hot, no LDS).
// A: reg-staged f32->bf16 into 2x2KB LDS dbuf (read-contiguous chunks).
// LDS total 16.9KB; target 2 blocks/CU = 32 waves (needs VGPR<=64).
__global__ void __launch_bounds__(1024, 8)
k_attn(const float* __restrict__ enc, const u16* __restrict__ w1p,
       const float* __restrict__ hpb, const float* __restrict__ Vw,
       const float* __restrict__ Vb, float* __restrict__ ctxp,
       float* __restrict__ stats) {
  __shared__ __align__(16) u16 smem[8448];   // loop: A dbuf 2x1024 u16; epi: 4224 f32

  const int t = threadIdx.x;
  const int bid = blockIdx.x;
  const int b = bid >> 5, tile = bid & 31;
  const size_t row0 = (size_t)b * 2048 + (size_t)tile * 64;

  const int l = t & 63, wv = t >> 6;         // 16 waves

  // B fragment source: contiguous per (ks, wave): + ks*8192 u16
  const u16* bbase = w1p + (size_t)wv * 512 + (size_t)l * 8;

  // A staging: threads 0..255, each one float4 (half-chunk) per step
  const int sr = t >> 2, sh = (t >> 1) & 1, sq = t & 1;
  const float* a_src = enc + (row0 + sr) * 1024 + sh * 8 + sq * 4;   // + ks*16
  const int a_dst = ((sr >> 5) * 64 + (sr & 31) + (sh << 5)) * 8 + sq * 4;

  f32x16 acc0, acc1;
  #pragma unroll
  for (int i = 0; i < 16; ++i) { acc0[i] = 0.f; acc1[i] = 0.f; }

  float4 av = {0.f, 0.f, 0.f, 0.f};
  // prologue: stage A(0) into buf0; A(1) in flight
  if (t < 256) {
    float4 p0 = *(const float4*)(a_src);
    u16x4 w4;
    w4[0] = f2bf(p0.x); w4[1] = f2bf(p0.y); w4[2] = f2bf(p0.z); w4[3] = f2bf(p0.w);
    *(u16x4*)(smem + a_dst) = w4;
    av = *(const float4*)(a_src + 16);
  }
  __syncthreads();

  #pragma unroll 2
  for (int ks = 0; ks < 64; ++ks) {
    const int cur = ks & 1;
    float4 nx = av;
    if (t < 256 && ks < 62) nx = *(const float4*)(a_src + (ks + 2) * 16);  // issue early
    if (t < 256 && ks < 63) {       // write A(ks+1) (value drained at prev barrier)
      u16x4 w4;
      w4[0] = f2bf(av.x); w4[1] = f2bf(av.y); w4[2] = f2bf(av.z); w4[3] = f2bf(av.w);
      *(u16x4*)(smem + ((cur ^ 1) << 10) + a_dst) = w4;
    }
    bf16x8 bfr = *(const bf16x8*)(bbase + (size_t)ks * 8192);   // L2-hot
    const u16* Ac = smem + (cur << 10);
    bf16x8 a0 = *(const bf16x8*)(Ac + l * 8);          // rows 0..31
    bf16x8 a1 = *(const bf16x8*)(Ac + 512 + l * 8);    // rows 32..63
    acc0 = __builtin_amdgcn_mfma_f32_32x32x16_bf16(a0, bfr, acc0, 0, 0, 0);
    acc1 = __builtin_amdgcn_mfma_f32_32x32x16_bf16(a1, bfr, acc1, 0, 0, 0);
    av = nx;
    __syncthreads();
  }

  // ---- epilogue (smem reused as f32): score -> exp -> stats
  float* fsm = (float*)smem;
  float* red = fsm;            // [64][17]
  float* scv = fsm + 1088;     // [64]
  float* pcv = fsm + 1152;     // [3072]

  const int ucol = (wv << 5) + (l & 31);
  const float vwv = Vw[ucol];
  const float hpv = hpb[(size_t)b * 512 + ucol];
  const int hi4 = (l >> 5) * 4;
  const bool writer = ((l & 31) == 0);
  // D mapping (32x32): col=lane&31 (u), row=(r&3)+8*(r>>2)+4*(lane>>5) (s)
  #pragma unroll
  for (int im = 0; im < 2; ++im) {
    #pragma unroll
    for (int r = 0; r < 16; ++r) {
      float s = vwv * fast_tanh((im ? acc1[r] : acc0[r]) + hpv);
      s += __shfl_xor(s, 1);
      s += __shfl_xor(s, 2);
      s += __shfl_xor(s, 4);
      s += __shfl_xor(s, 8);
      s += __shfl_xor(s, 16);
      if (writer) {
        int sl = im * 32 + (r & 3) + 8 * (r >> 2) + hi4;
        red[sl * 17 + wv] = s;
      }
    }
  }
  __syncthreads();
  if (t < 64) {
    float s = Vb[0];
    #pragma unroll
    for (int wq = 0; wq < 16; ++wq) s += red[t * 17 + wq];
    float e = __expf(s);   // |score| bounded (~||Vw||_1): f32-safe without max-sub
    scv[t] = e;
    float p = e;
    p += __shfl_xor(p, 1);  p += __shfl_xor(p, 2);  p += __shfl_xor(p, 4);
    p += __shfl_xor(p, 8);  p += __shfl_xor(p, 16); p += __shfl_xor(p, 32);
    if (t == 0) stats[bid] = p;
  }
  __syncthreads();

  // ---- tail-PV: unnormalized partial ctx from own (L3-hot) f32 enc tile
  {
    const int c4 = (t & 255) * 4;
    const int rq = t >> 8;                 // 0..3 -> rows rq*16..+16
    const float* ep = enc + (row0 + rq * 16) * 1024 + c4;
    float ax = 0.f, ay = 0.f, az = 0.f, aw2 = 0.f;
    #pragma unroll 4
    for (int r = 0; r < 16; ++r) {
      float4 v = *(const float4*)(ep + (size_t)r * 1024);
      float sc = scv[rq * 16 + r];
      ax += sc * v.x; ay += sc * v.y; az += sc * v.z; aw2 += sc * v.w;
    }
    if (rq) {
      float4 st = {ax, ay, az, aw2};
      *(float4*)&pcv[(rq - 1) * 1024 + c4] = st;
    }
    __syncthreads();
    if (rq == 0) {
      float4 p1 = *(const float4*)&pcv[c4];
      float4 p2 = *(const float4*)&pcv[1024 + c4];
      float4 p3 = *(const float4*)&pcv[2048 + c4];
      float4 o = {ax + p1.x + p2.x + p3.x, ay + p1.y + p2.y + p3.y,
                  az + p1.z + p2.z + p3.z, aw2 + p1.w + p2.w + p3.w};
      *(float4*)&ctxp[(size_t)bid * 1024 + c4] = o;
    }
  }
}

// ---------------- combine tile partials -> xin[:, :1024]; gather emb -> xin[:, 1024:]
__global__ void k_attn_reduce(const float* __restrict__ ctxp, const float* __restrict__ stats,
                              const int* __restrict__ x, const float* __restrict__ emb,
                              float* __restrict__ xin) {
  __shared__ float ps[32];
  __shared__ float invs;
  const int b = blockIdx.x, t = threadIdx.x;
  if (t < 32) ps[t] = stats[b * 32 + t];
  __syncthreads();
  if (t == 0) {
    float s = 0.f;
    #pragma unroll
    for (int i = 0; i < 32; ++i) s += ps[i];
    invs = 1.f / s;
  }
  __syncthreads();
  const float inv = invs;
  #pragma unroll
  for (int i = 0; i < 4; ++i) {
    int c = t + i * 256;
    float a = 0.f;
    for (int chv = 0; chv < 32; ++chv)
      a += ctxp[((size_t)b * 32 + chv) * 1024 + c];
    xin[(size_t)b * 1280 + c] = a * inv;
  }
  xin[(size_t)b * 1280 + 1024 + t] = emb[(size_t)x[b] * 256 + t];
}

// ---------------- z_part = xin @ K  (dir x ksplit x jtile), f32
__global__ void k_lstm_gemm(const float* __restrict__ xin, const float* __restrict__ Kf,
                            const float* __restrict__ Kb, float* __restrict__ zpart) {
  __shared__ float xl[32][68];   // [kk][b], padded
  const int t = threadIdx.x;
  const int bid = blockIdx.x;          // 2 dir * 64 jt * 2 ks = 256
  const int dir = bid >> 7;
  const int jt  = (bid >> 1) & 63;
  const int ks  = bid & 1;
  const float* K = dir ? Kb : Kf;
  const int j  = jt * 32 + (t & 31);
  const int tb = t >> 5;               // 8 groups of 8 b
  const int brow = t >> 2, kq = (t & 3) * 8;
  float acc[8] = {0,0,0,0,0,0,0,0};
  for (int k0 = ks * 640; k0 < ks * 640 + 640; k0 += 32) {
    float4 x0 = *(const float4*)&xin[(size_t)brow * 1280 + k0 + kq];
    float4 x1 = *(const float4*)&xin[(size_t)brow * 1280 + k0 + kq + 4];
    __syncthreads();
    xl[kq+0][brow]=x0.x; xl[kq+1][brow]=x0.y; xl[kq+2][brow]=x0.z; xl[kq+3][brow]=x0.w;
    xl[kq+4][brow]=x1.x; xl[kq+5][brow]=x1.y; xl[kq+6][brow]=x1.z; xl[kq+7][brow]=x1.w;
    __syncthreads();
    const float* Kp = K + (size_t)k0 * 2048 + j;
    #pragma unroll 8
    for (int kk = 0; kk < 32; ++kk) {
      float wv = Kp[(size_t)kk * 2048];
      float4 v0 = *(const float4*)&xl[kk][tb * 8];
      float4 v1 = *(const float4*)&xl[kk][tb * 8 + 4];
      acc[0] += v0.x * wv; acc[1] += v0.y * wv; acc[2] += v0.z * wv; acc[3] += v0.w * wv;
      acc[4] += v1.x * wv; acc[5] += v1.y * wv; acc[6] += v1.z * wv; acc[7] += v1.w * wv;
    }
  }
  float* zp = zpart + ((size_t)dir * 2 + ks) * 64 * 2048;
  #pragma unroll
  for (int i = 0; i < 8; ++i)
    zp[(size_t)(tb * 8 + i) * 2048 + j] = acc[i];
}

// ---------------- gates: c = sig(i)*tanh(g); h = sig(o)*tanh(c); also h -> hi/lo bf16
__global__ void k_gates(const float* __restrict__ zpart, const float* __restrict__ bfv,
                        const float* __restrict__ bbv, float* __restrict__ dout,
                        u16* __restrict__ hhl) {
  const int dir = blockIdx.x >> 6, b = blockIdx.x & 63, u = threadIdx.x;
  const float* bias = dir ? bbv : bfv;
  const float* z0 = zpart + ((size_t)dir * 2 + 0) * 131072 + (size_t)b * 2048;
  const float* z1 = zpart + ((size_t)dir * 2 + 1) * 131072 + (size_t)b * 2048;
  float zi = z0[u]        + z1[u]        + bias[u];
  float zg = z0[1024 + u] + z1[1024 + u] + bias[1024 + u];
  float zo = z0[1536 + u] + z1[1536 + u] + bias[1536 + u];
  float c = fast_sig(zi) * fast_tanh(zg);
  float h = fast_sig(zo) * fast_tanh(c);
  size_t base = 3200000u + (size_t)dir * 65536u;
  dout[base + (size_t)b * 512 + u] = h;
  dout[base + 32768u + (size_t)b * 512 + u] = c;
  u16 hi = f2bf(h);
  u16 lo = f2bf(h - bf2f(hi));
  hhl[(size_t)b * 1024 + dir * 512 + u] = hi;
  hhl[65536u + (size_t)b * 1024 + dir * 512 + u] = lo;
}

// ---------------- logits = [hf hb] @ fc_w + fc_b  via MFMA, fcw read DIRECTLY as f32
// 392 blocks x 128 cols, 256 thr / 4 waves (1M x 4N, wave 64x32). B: f32 tile ->
// LDS [32][136] -> transpose-read + cvt. A: h hi/lo bf16 from L2-hot hhl.
__global__ void __launch_bounds__(256)
k_fc_mfma(const float* __restrict__ fcw, const u16* __restrict__ hhl,
          const float* __restrict__ fcb, float* __restrict__ logits) {
  __shared__ float Bs[2][32 * 136];
  const int t = threadIdx.x;
  const int j0 = blockIdx.x * 128;
  const int l = t & 63, w = t >> 6;
  const int ln = l & 15, lg = l >> 4;
  const int srow = t >> 3, scol = (t & 7) * 16;
  const bool interior = (j0 + 128 <= 50000);

  f32x4 acc[4][2];
  #pragma unroll
  for (int im = 0; im < 4; ++im)
    #pragma unroll
    for (int nf = 0; nf < 2; ++nf) acc[im][nf] = f32x4{0.f, 0.f, 0.f, 0.f};

  float4 pre[4];
  {
    const float* src = fcw + (size_t)srow * 50000 + j0 + scol;
    if (interior) {
      #pragma unroll
      for (int q = 0; q < 4; ++q) pre[q] = *(const float4*)(src + q * 4);
    } else {
      #pragma unroll
      for (int q = 0; q < 4; ++q) {
        int jb = j0 + scol + q * 4;
        pre[q].x = (jb + 0 < 50000) ? src[q*4 + 0] : 0.f;
        pre[q].y = (jb + 1 < 50000) ? src[q*4 + 1] : 0.f;
        pre[q].z = (jb + 2 < 50000) ? src[q*4 + 2] : 0.f;
        pre[q].w = (jb + 3 < 50000) ? src[q*4 + 3] : 0.f;
      }
    }
    #pragma unroll
    for (int q = 0; q < 4; ++q)
      *(float4*)&Bs[0][srow * 136 + scol + q * 4] = pre[q];
  }
  __syncthreads();

  for (int ks = 0; ks < 32; ++ks) {
    const int cur = ks & 1;
    if (ks < 31) {
      const float* src = fcw + (size_t)(ks + 1) * 32 * 50000 + (size_t)srow * 50000 + j0 + scol;
      if (interior) {
        #pragma unroll
        for (int q = 0; q < 4; ++q) pre[q] = *(const float4*)(src + q * 4);
      } else {
        #pragma unroll
        for (int q = 0; q < 4; ++q) {
          int jb = j0 + scol + q * 4;
          pre[q].x = (jb + 0 < 50000) ? src[q*4 + 0] : 0.f;
          pre[q].y = (jb + 1 < 50000) ? src[q*4 + 1] : 0.f;
          pre[q].z = (jb + 2 < 50000) ? src[q*4 + 2] : 0.f;
          pre[q].w = (jb + 3 < 50000) ? src[q*4 + 3] : 0.f;
        }
      }
    }
    bf16x8 ahi[4], alo[4];
    #pragma unroll
    for (int im = 0; im < 4; ++im) {
      const u16* ha = hhl + (size_t)(im * 16 + ln) * 1024 + ks * 32 + lg * 8;
      ahi[im] = *(const bf16x8*)(ha);
      alo[im] = *(const bf16x8*)(ha + 65536);
    }
    bf16x8 bfr[2];
    #pragma unroll
    for (int nf = 0; nf < 2; ++nf) {
      u16x8 pv;
      #pragma unroll
      for (int i = 0; i < 8; ++i)
        pv[i] = f2bf(Bs[cur][(lg * 8 + i) * 136 + w * 32 + nf * 16 + ln]);
      bfr[nf] = *(bf16x8*)&pv;
    }
    #pragma unroll
    for (int im = 0; im < 4; ++im)
      #pragma unroll
      for (int nf = 0; nf < 2; ++nf) {
        acc[im][nf] = __builtin_amdgcn_mfma_f32_16x16x32_bf16(alo[im], bfr[nf], acc[im][nf], 0, 0, 0);
        acc[im][nf] = __builtin_amdgcn_mfma_f32_16x16x32_bf16(ahi[im], bfr[nf], acc[im][nf], 0, 0, 0);
      }
    if (ks < 31) {
      #pragma unroll
      for (int q = 0; q < 4; ++q)
        *(float4*)&Bs[cur ^ 1][srow * 136 + scol + q * 4] = pre[q];
    }
    __syncthreads();
  }

  #pragma unroll
  for (int nf = 0; nf < 2; ++nf) {
    int c = j0 + w * 32 + nf * 16 + ln;
    if (c < 50000) {
      float fb = fcb[c];
      #pragma unroll
      for (int im = 0; im < 4; ++im)
        #pragma unroll
        for (int r = 0; r < 4; ++r) {
          int row = im * 16 + lg * 4 + r;
          logits[(size_t)row * 50000 + c] = acc[im][nf][r] + fb;
        }
    }
  }
}

// ---------------- fallback f32 fc (used when ws too small for scratch arena)
__global__ void __launch_bounds__(256)
k_fc_f32(const float* __restrict__ dout_ro, const float* __restrict__ fcw,
         const float* __restrict__ fcb, float* __restrict__ logits) {
  __shared__ float ol[64][68];
  __shared__ float wl[64][132];
  const int t = threadIdx.x;
  const int j0 = blockIdx.x * 128;
  const int tb = t >> 5, tj = t & 31;
  const float* hf = dout_ro + 3200000u;
  const float* hb = dout_ro + 3200000u + 65536u;
  float acc[8][4];
  #pragma unroll
  for (int bi = 0; bi < 8; ++bi)
    #pragma unroll
    for (int ji = 0; ji < 4; ++ji) acc[bi][ji] = 0.f;

  for (int k0 = 0; k0 < 1024; k0 += 64) {
    __syncthreads();
    {
      int bb = t >> 2, kq = (t & 3) * 16;
      const float* src = (k0 < 512) ? (hf + (size_t)bb * 512 + k0 + kq)
                                    : (hb + (size_t)bb * 512 + (k0 - 512) + kq);
      #pragma unroll
      for (int i = 0; i < 4; ++i) {
        float4 v = *(const float4*)(src + i * 4);
        ol[kq + i*4 + 0][bb] = v.x;
        ol[kq + i*4 + 1][bb] = v.y;
        ol[kq + i*4 + 2][bb] = v.z;
        ol[kq + i*4 + 3][bb] = v.w;
      }
    }
    {
      int kk = t >> 2, jh = (t & 3) * 32;
      const float* wsrc = fcw + (size_t)(k0 + kk) * 50000 + j0 + jh;
      #pragma unroll
      for (int i = 0; i < 8; ++i) {
        int j = j0 + jh + i * 4;
        float4 v;
        if (j + 3 < 50000) {
          v = *(const float4*)(wsrc + i * 4);
        } else {
          v.x = (j + 0 < 50000) ? wsrc[i*4 + 0] : 0.f;
          v.y = (j + 1 < 50000) ? wsrc[i*4 + 1] : 0.f;
          v.z = (j + 2 < 50000) ? wsrc[i*4 + 2] : 0.f;
          v.w = 0.f;
        }
        *(float4*)&wl[kk][jh + i * 4] = v;
      }
    }
    __syncthreads();
    #pragma unroll 4
    for (int kk = 0; kk < 64; ++kk) {
      float4 wv = *(const float4*)&wl[kk][tj * 4];
      float4 q0 = *(const float4*)&ol[kk][tb * 8];
      float4 q1 = *(const float4*)&ol[kk][tb * 8 + 4];
      float obv[8] = {q0.x, q0.y, q0.z, q0.w, q1.x, q1.y, q1.z, q1.w};
      #pragma unroll
      for (int bi = 0; bi < 8; ++bi) {
        acc[bi][0] += obv[bi] * wv.x;
        acc[bi][1] += obv[bi] * wv.y;
        acc[bi][2] += obv[bi] * wv.z;
        acc[bi][3] += obv[bi] * wv.w;
      }
    }
  }

  const int j = j0 + tj * 4;
  if (j + 3 < 50000) {
    float4 fb = *(const float4*)(fcb + j);
    #pragma unroll
    for (int bi = 0; bi < 8; ++bi) {
      float4 r;
      r.x = acc[bi][0] + fb.x; r.y = acc[bi][1] + fb.y;
      r.z = acc[bi][2] + fb.z; r.w = acc[bi][3] + fb.w;
      *(float4*)&logits[(size_t)(tb * 8 + bi) * 50000 + j] = r;
    }
  } else {
    for (int ji = 0; ji < 4; ++ji) {
      if (j + ji < 50000) {
        float fb = fcb[j + ji];
        for (int bi = 0; bi < 8; ++bi)
          logits[(size_t)(tb * 8 + bi) * 50000 + j + ji] = acc[bi][ji] + fb;
      }
    }
  }
}

extern "C" void kernel_launch(void* const* d_in, const int* in_sizes, int n_in,
                              void* d_out, int out_size, void* d_ws, size_t ws_size,
                              hipStream_t stream) {
  const int*   x    = (const int*)  d_in[0];
  const float* cfwd = (const float*)d_in[1];
  const float* cbwd = (const float*)d_in[2];
  const float* enc  = (const float*)d_in[3];
  const float* emb  = (const float*)d_in[4];
  const float* W1w  = (const float*)d_in[5];
  const float* W1b  = (const float*)d_in[6];
  const float* W2w  = (const float*)d_in[7];
  const float* W2b  = (const float*)d_in[8];
  const float* W3w  = (const float*)d_in[9];
  const float* W3b  = (const float*)d_in[10];
  const float* Vw   = (const float*)d_in[11];
  const float* Vb   = (const float*)d_in[12];
  const float* Kf   = (const float*)d_in[13];
  const float* bfv  = (const float*)d_in[14];
  const float* Kb   = (const float*)d_in[15];
  const float* bbv  = (const float*)d_in[16];
  const float* fcw  = (const float*)d_in[17];
  const float* fcb  = (const float*)d_in[18];
  float* out = (float*)d_out;

  const bool haveWs = (ws_size >= SCRATCH_BYTES);
  float* S = haveWs ? (float*)d_ws : out;   // fallback carve ends 3065856 < 3200000
  u16*   w1p   = (u16*)S;
  float* hpb   = S + OF_HPB;
  float* ctxp  = S + OF_CTXP;
  float* stats = S + OF_STATS;
  float* xin   = S + OF_XIN;
  float* zpart = S + OF_ZPART;
  u16*   hhl   = (u16*)(S + OF_HHL);

  k_prep_w1<<<64, 256, 0, stream>>>(W1w, w1p);
  k_prep_hp<<<64, 256, 0, stream>>>(cfwd, cbwd, W2w, W2b, W3w, W3b, W1b, hpb);
  k_attn<<<2048, 1024, 0, stream>>>(enc, w1p, hpb, Vw, Vb, ctxp, stats);
  k_attn_reduce<<<64, 256, 0, stream>>>(ctxp, stats, x, emb, xin);
  k_lstm_gemm<<<256, 256, 0, stream>>>(xin, Kf, Kb, zpart);
  k_gates<<<128, 512, 0, stream>>>(zpart, bfv, bbv, out, hhl);
  if (haveWs) k_fc_mfma<<<392, 256, 0, stream>>>(fcw, hhl, fcb, out);
  else        k_fc_f32<<<391, 256, 0, stream>>>(out, fcw, fcb, out);
}

// Round 9
// 540.474 us; speedup vs baseline: 1.0171x; 1.0171x over previous
//
#include <hip/hip_runtime.h>

using u16 = unsigned short;
typedef float f32x4 __attribute__((ext_vector_type(4)));
typedef float f32x16 __attribute__((ext_vector_type(16)));
typedef __bf16 bf16x8 __attribute__((ext_vector_type(8)));
typedef u16 u16x8 __attribute__((ext_vector_type(8)));
typedef u16 u16x4 __attribute__((ext_vector_type(4)));

// dims: B=64, S=2048, ENC=1024, U=512, E=256, V=50000, IN=1280
// scratch layout (float units)
static constexpr int OF_HPB   = 262144;    // w1p: 512K u16 = 262144 floats
static constexpr int OF_CTXP  = 294912;    // hpb: 64*512
static constexpr int OF_STATS = 2392064;   // ctxp: 2048*1024
static constexpr int OF_XIN   = 2394112;   // stats: 2048
static constexpr int OF_ZPART = 2476032;   // xin: 64*1280
static constexpr int OF_HHL   = 3000320;   // zpart: 4*64*2048; hhl: 2*64*1024 u16
static constexpr size_t SCRATCH_FLOATS = 3065856;
static constexpr size_t SCRATCH_BYTES  = SCRATCH_FLOATS * 4ull;   // ~12.3 MB

__device__ __forceinline__ u16 f2bf(float f) {
  unsigned u = __float_as_uint(f);
  u += 0x7FFFu + ((u >> 16) & 1u);   // RNE; inputs finite
  return (u16)(u >> 16);
}
__device__ __forceinline__ float bf2f(u16 u) {
  return __uint_as_float((unsigned)u << 16);
}
__device__ __forceinline__ float fast_tanh(float x) {
  x = fminf(fmaxf(x, -20.f), 20.f);
  float e = __expf(2.f * x);
  return (e - 1.f) / (e + 1.f);
}
__device__ __forceinline__ float fast_sig(float x) { return 1.f / (1.f + __expf(-x)); }

// ---------------- W1 (1024x512 f32 [k][u]) -> bf16 packed for 32x32x16 B-frags:
// w1p[ks16*8192 + (wv*64 + l)*8 + e] = W1[ks16*16 + (l>>5)*8 + e][wv*32 + (l&31)]
__global__ void k_prep_w1(const float* __restrict__ W1w, u16* __restrict__ w1p) {
  __shared__ float tile[16][516];
  const int t = threadIdx.x;          // 256
  const int ks = blockIdx.x;          // 64
  {
    int kk = t >> 4, u0 = (t & 15) * 32;
    const float* src = W1w + (size_t)(ks * 16 + kk) * 512 + u0;
    #pragma unroll
    for (int i = 0; i < 8; ++i)
      *(float4*)&tile[kk][u0 + i * 4] = *(const float4*)(src + i * 4);
  }
  __syncthreads();
  #pragma unroll
  for (int q = 0; q < 4; ++q) {
    int c = t + q * 256;              // chunk 0..1023
    int wv = c >> 6, l = c & 63;
    int u = wv * 32 + (l & 31), koct = l >> 5;
    u16x8 p;
    #pragma unroll
    for (int e = 0; e < 8; ++e) p[e] = f2bf(tile[koct * 8 + e][u]);
    *(u16x8*)(w1p + (size_t)ks * 8192 + (size_t)c * 8) = p;
  }
}

// ---------------- hpb[b][u] = c_fwd@W2 + W2_b + c_bwd@W3 + W3_b + W1_b
__global__ void k_prep_hp(const float* __restrict__ cf, const float* __restrict__ cb,
                          const float* __restrict__ W2w, const float* __restrict__ W2b,
                          const float* __restrict__ W3w, const float* __restrict__ W3b,
                          const float* __restrict__ W1b, float* __restrict__ hpb) {
  __shared__ float cfl[512], cbl[512];
  const int b = blockIdx.x, t = threadIdx.x;
  cfl[t] = cf[(size_t)b * 512 + t];       cfl[t + 256] = cf[(size_t)b * 512 + t + 256];
  cbl[t] = cb[(size_t)b * 512 + t];       cbl[t + 256] = cb[(size_t)b * 512 + t + 256];
  __syncthreads();
  const int u1 = t, u2 = t + 256;
  float a1 = W2b[u1] + W3b[u1] + W1b[u1];
  float a2 = W2b[u2] + W3b[u2] + W1b[u2];
  for (int k = 0; k < 512; ++k) {
    float c1 = cfl[k], c2 = cbl[k];
    const float* r2 = W2w + (size_t)k * 512;
    const float* r3 = W3w + (size_t)k * 512;
    a1 += c1 * r2[u1] + c2 * r3[u1];
    a2 += c1 * r2[u2] + c2 * r3[u2];
  }
  hpb[(size_t)b * 512 + u1] = a1;
  hpb[(size_t)b * 512 + u2] = a2;
}

// ---------------- fused attention v4: score GEMM (32x32x16, BK=16) -> exp/stats
// -> tail-PV. 2048 blocks = 64 b x 32 tiles. 1024 thr = 16 waves, 2 blocks/CU.
// K-loop barrier = raw s_barrier + lgkmcnt(0) ONLY (no vmcnt drain): global
// loads (B->reg, A-prefetch->reg) stay in flight across barriers; compiler
// inserts counted vmcnt before their uses. (__syncthreads drained a just-issued
// HBM load every iter -> r8 was drain-bound: occ 90% / MFMA 17% / HBM 20%.)
// A-prefetch 2 iters deep (av0/av1); B prefetched 1 step ahead.
__global__ void __launch_bounds__(1024, 8)
k_attn(const float* __restrict__ enc, const u16* __restrict__ w1p,
       const float* __restrict__ hpb, const float* __restrict__ Vw,
       const float* __restrict__ Vb, float* __restrict__ ctxp,
       float* __restrict__ stats) {
  __shared__ __align__(16) u16 smem[8448];   // loop: A dbuf 2x1024 u16; epi: 4224 f32

  const int t = threadIdx.x;
  const int bid = blockIdx.x;
  const int b = bid >> 5, tile = bid & 31;
  const size_t row0 = (size_t)b * 2048 + (size_t)tile * 64;

  const int l = t & 63, wv = t >> 6;         // 16 waves

  // B fragment source: contiguous per (ks, wave): + ks*8192 u16
  const u16* bbase = w1p + (size_t)wv * 512 + (size_t)l * 8;

  // A staging: threads 0..255, each one float4 (half-chunk) per step
  const int sr = t >> 2, sh = (t >> 1) & 1, sq = t & 1;
  const float* a_src = enc + (row0 + sr) * 1024 + sh * 8 + sq * 4;   // + ks*16
  const int a_dst = ((sr >> 5) * 64 + (sr & 31) + (sh << 5)) * 8 + sq * 4;

  f32x16 acc0, acc1;
  #pragma unroll
  for (int i = 0; i < 16; ++i) { acc0[i] = 0.f; acc1[i] = 0.f; }

  float4 av0 = {0.f,0.f,0.f,0.f}, av1 = {0.f,0.f,0.f,0.f};
  // prologue: stage A(0) into buf0; A(1),A(2) in flight
  if (t < 256) {
    float4 p0 = *(const float4*)(a_src);
    u16x4 w4;
    w4[0] = f2bf(p0.x); w4[1] = f2bf(p0.y); w4[2] = f2bf(p0.z); w4[3] = f2bf(p0.w);
    *(u16x4*)(smem + a_dst) = w4;
    av0 = *(const float4*)(a_src + 16);
    av1 = *(const float4*)(a_src + 32);
  }
  bf16x8 bcur = *(const bf16x8*)(bbase);
  asm volatile("s_waitcnt lgkmcnt(0)" ::: "memory");
  __builtin_amdgcn_s_barrier();
  __builtin_amdgcn_sched_barrier(0);

  #pragma unroll 2
  for (int ks = 0; ks < 64; ++ks) {
    const int cur = ks & 1;
    if (t < 256 && ks < 63) {       // write A(ks+1) (av0, loaded 2 iters ago)
      u16x4 w4;
      w4[0] = f2bf(av0.x); w4[1] = f2bf(av0.y); w4[2] = f2bf(av0.z); w4[3] = f2bf(av0.w);
      *(u16x4*)(smem + ((cur ^ 1) << 10) + a_dst) = w4;
      av0 = av1;
      if (ks < 61) av1 = *(const float4*)(a_src + (ks + 3) * 16);   // A(ks+3)
    }
    bf16x8 bnxt = bcur;
    if (ks < 63) bnxt = *(const bf16x8*)(bbase + (size_t)(ks + 1) * 8192);  // L2-hot
    const u16* Ac = smem + (cur << 10);
    bf16x8 a0 = *(const bf16x8*)(Ac + l * 8);          // rows 0..31
    bf16x8 a1 = *(const bf16x8*)(Ac + 512 + l * 8);    // rows 32..63
    acc0 = __builtin_amdgcn_mfma_f32_32x32x16_bf16(a0, bcur, acc0, 0, 0, 0);
    acc1 = __builtin_amdgcn_mfma_f32_32x32x16_bf16(a1, bcur, acc1, 0, 0, 0);
    bcur = bnxt;
    // raw barrier: LDS visibility only (lgkmcnt); vmem stays in flight
    asm volatile("s_waitcnt lgkmcnt(0)" ::: "memory");
    __builtin_amdgcn_s_barrier();
    __builtin_amdgcn_sched_barrier(0);
  }

  // ---- epilogue (smem reused as f32): score -> exp -> stats
  float* fsm = (float*)smem;
  float* red = fsm;            // [64][17]
  float* scv = fsm + 1088;     // [64]
  float* pcv = fsm + 1152;     // [3072]

  const int ucol = (wv << 5) + (l & 31);
  const float vwv = Vw[ucol];
  const float hpv = hpb[(size_t)b * 512 + ucol];
  const int hi4 = (l >> 5) * 4;
  const bool writer = ((l & 31) == 0);
  // D mapping (32x32): col=lane&31 (u), row=(r&3)+8*(r>>2)+4*(lane>>5) (s)
  #pragma unroll
  for (int im = 0; im < 2; ++im) {
    #pragma unroll
    for (int r = 0; r < 16; ++r) {
      float s = vwv * fast_tanh((im ? acc1[r] : acc0[r]) + hpv);
      s += __shfl_xor(s, 1);
      s += __shfl_xor(s, 2);
      s += __shfl_xor(s, 4);
      s += __shfl_xor(s, 8);
      s += __shfl_xor(s, 16);
      if (writer) {
        int sl = im * 32 + (r & 3) + 8 * (r >> 2) + hi4;
        red[sl * 17 + wv] = s;
      }
    }
  }
  __syncthreads();
  if (t < 64) {
    float s = Vb[0];
    #pragma unroll
    for (int wq = 0; wq < 16; ++wq) s += red[t * 17 + wq];
    float e = __expf(s);   // |score| bounded (~||Vw||_1): f32-safe without max-sub
    scv[t] = e;
    float p = e;
    p += __shfl_xor(p, 1);  p += __shfl_xor(p, 2);  p += __shfl_xor(p, 4);
    p += __shfl_xor(p, 8);  p += __shfl_xor(p, 16); p += __shfl_xor(p, 32);
    if (t == 0) stats[bid] = p;
  }
  __syncthreads();

  // ---- tail-PV: unnormalized partial ctx from own (L3-hot) f32 enc tile
  {
    const int c4 = (t & 255) * 4;
    const int rq = t >> 8;                 // 0..3 -> rows rq*16..+16
    const float* ep = enc + (row0 + rq * 16) * 1024 + c4;
    float ax = 0.f, ay = 0.f, az = 0.f, aw2 = 0.f;
    #pragma unroll 4
    for (int r = 0; r < 16; ++r) {
      float4 v = *(const float4*)(ep + (size_t)r * 1024);
      float sc = scv[rq * 16 + r];
      ax += sc * v.x; ay += sc * v.y; az += sc * v.z; aw2 += sc * v.w;
    }
    if (rq) {
      float4 st = {ax, ay, az, aw2};
      *(float4*)&pcv[(rq - 1) * 1024 + c4] = st;
    }
    __syncthreads();
    if (rq == 0) {
      float4 p1 = *(const float4*)&pcv[c4];
      float4 p2 = *(const float4*)&pcv[1024 + c4];
      float4 p3 = *(const float4*)&pcv[2048 + c4];
      float4 o = {ax + p1.x + p2.x + p3.x, ay + p1.y + p2.y + p3.y,
                  az + p1.z + p2.z + p3.z, aw2 + p1.w + p2.w + p3.w};
      *(float4*)&ctxp[(size_t)bid * 1024 + c4] = o;
    }
  }
}

// ---------------- combine tile partials -> xin[:, :1024]; gather emb -> xin[:, 1024:]
__global__ void k_attn_reduce(const float* __restrict__ ctxp, const float* __restrict__ stats,
                              const int* __restrict__ x, const float* __restrict__ emb,
                              float* __restrict__ xin) {
  __shared__ float ps[32];
  __shared__ float invs;
  const int b = blockIdx.x, t = threadIdx.x;
  if (t < 32) ps[t] = stats[b * 32 + t];
  __syncthreads();
  if (t == 0) {
    float s = 0.f;
    #pragma unroll
    for (int i = 0; i < 32; ++i) s += ps[i];
    invs = 1.f / s;
  }
  __syncthreads();
  const float inv = invs;
  #pragma unroll
  for (int i = 0; i < 4; ++i) {
    int c = t + i * 256;
    float a = 0.f;
    for (int chv = 0; chv < 32; ++chv)
      a += ctxp[((size_t)b * 32 + chv) * 1024 + c];
    xin[(size_t)b * 1280 + c] = a * inv;
  }
  xin[(size_t)b * 1280 + 1024 + t] = emb[(size_t)x[b] * 256 + t];
}

// ---------------- z_part = xin @ K  (dir x ksplit x jtile), f32
__global__ void k_lstm_gemm(const float* __restrict__ xin, const float* __restrict__ Kf,
                            const float* __restrict__ Kb, float* __restrict__ zpart) {
  __shared__ float xl[32][68];   // [kk][b], padded
  const int t = threadIdx.x;
  const int bid = blockIdx.x;          // 2 dir * 64 jt * 2 ks = 256
  const int dir = bid >> 7;
  const int jt  = (bid >> 1) & 63;
  const int ks  = bid & 1;
  const float* K = dir ? Kb : Kf;
  const int j  = jt * 32 + (t & 31);
  const int tb = t >> 5;               // 8 groups of 8 b
  const int brow = t >> 2, kq = (t & 3) * 8;
  float acc[8] = {0,0,0,0,0,0,0,0};
  for (int k0 = ks * 640; k0 < ks * 640 + 640; k0 += 32) {
    float4 x0 = *(const float4*)&xin[(size_t)brow * 1280 + k0 + kq];
    float4 x1 = *(const float4*)&xin[(size_t)brow * 1280 + k0 + kq + 4];
    __syncthreads();
    xl[kq+0][brow]=x0.x; xl[kq+1][brow]=x0.y; xl[kq+2][brow]=x0.z; xl[kq+3][brow]=x0.w;
    xl[kq+4][brow]=x1.x; xl[kq+5][brow]=x1.y; xl[kq+6][brow]=x1.z; xl[kq+7][brow]=x1.w;
    __syncthreads();
    const float* Kp = K + (size_t)k0 * 2048 + j;
    #pragma unroll 8
    for (int kk = 0; kk < 32; ++kk) {
      float wv = Kp[(size_t)kk * 2048];
      float4 v0 = *(const float4*)&xl[kk][tb * 8];
      float4 v1 = *(const float4*)&xl[kk][tb * 8 + 4];
      acc[0] += v0.x * wv; acc[1] += v0.y * wv; acc[2] += v0.z * wv; acc[3] += v0.w * wv;
      acc[4] += v1.x * wv; acc[5] += v1.y * wv; acc[6] += v1.z * wv; acc[7] += v1.w * wv;
    }
  }
  float* zp = zpart + ((size_t)dir * 2 + ks) * 64 * 2048;
  #pragma unroll
  for (int i = 0; i < 8; ++i)
    zp[(size_t)(tb * 8 + i) * 2048 + j] = acc[i];
}

// ---------------- gates: c = sig(i)*tanh(g); h = sig(o)*tanh(c); also h -> hi/lo bf16
__global__ void k_gates(const float* __restrict__ zpart, const float* __restrict__ bfv,
                        const float* __restrict__ bbv, float* __restrict__ dout,
                        u16* __restrict__ hhl) {
  const int dir = blockIdx.x >> 6, b = blockIdx.x & 63, u = threadIdx.x;
  const float* bias = dir ? bbv : bfv;
  const float* z0 = zpart + ((size_t)dir * 2 + 0) * 131072 + (size_t)b * 2048;
  const float* z1 = zpart + ((size_t)dir * 2 + 1) * 131072 + (size_t)b * 2048;
  float zi = z0[u]        + z1[u]        + bias[u];
  float zg = z0[1024 + u] + z1[1024 + u] + bias[1024 + u];
  float zo = z0[1536 + u] + z1[1536 + u] + bias[1536 + u];
  float c = fast_sig(zi) * fast_tanh(zg);
  float h = fast_sig(zo) * fast_tanh(c);
  size_t base = 3200000u + (size_t)dir * 65536u;
  dout[base + (size_t)b * 512 + u] = h;
  dout[base + 32768u + (size_t)b * 512 + u] = c;
  u16 hi = f2bf(h);
  u16 lo = f2bf(h - bf2f(hi));
  hhl[(size_t)b * 1024 + dir * 512 + u] = hi;
  hhl[65536u + (size_t)b * 1024 + dir * 512 + u] = lo;
}

// ---------------- logits = [hf hb] @ fc_w + fc_b  via MFMA, fcw read DIRECTLY as f32
// 392 blocks x 128 cols, 256 thr / 4 waves (1M x 4N, wave 64x32). B: f32 tile ->
// LDS [32][136] -> transpose-read + cvt. A: h hi/lo bf16 from L2-hot hhl.
__global__ void __launch_bounds__(256)
k_fc_mfma(const float* __restrict__ fcw, const u16* __restrict__ hhl,
          const float* __restrict__ fcb, float* __restrict__ logits) {
  __shared__ float Bs[2][32 * 136];
  const int t = threadIdx.x;
  const int j0 = blockIdx.x * 128;
  const int l = t & 63, w = t >> 6;
  const int ln = l & 15, lg = l >> 4;
  const int srow = t >> 3, scol = (t & 7) * 16;
  const bool interior = (j0 + 128 <= 50000);

  f32x4 acc[4][2];
  #pragma unroll
  for (int im = 0; im < 4; ++im)
    #pragma unroll
    for (int nf = 0; nf < 2; ++nf) acc[im][nf] = f32x4{0.f, 0.f, 0.f, 0.f};

  float4 pre[4];
  {
    const float* src = fcw + (size_t)srow * 50000 + j0 + scol;
    if (interior) {
      #pragma unroll
      for (int q = 0; q < 4; ++q) pre[q] = *(const float4*)(src + q * 4);
    } else {
      #pragma unroll
      for (int q = 0; q < 4; ++q) {
        int jb = j0 + scol + q * 4;
        pre[q].x = (jb + 0 < 50000) ? src[q*4 + 0] : 0.f;
        pre[q].y = (jb + 1 < 50000) ? src[q*4 + 1] : 0.f;
        pre[q].z = (jb + 2 < 50000) ? src[q*4 + 2] : 0.f;
        pre[q].w = (jb + 3 < 50000) ? src[q*4 + 3] : 0.f;
      }
    }
    #pragma unroll
    for (int q = 0; q < 4; ++q)
      *(float4*)&Bs[0][srow * 136 + scol + q * 4] = pre[q];
  }
  __syncthreads();

  for (int ks = 0; ks < 32; ++ks) {
    const int cur = ks & 1;
    if (ks < 31) {
      const float* src = fcw + (size_t)(ks + 1) * 32 * 50000 + (size_t)srow * 50000 + j0 + scol;
      if (interior) {
        #pragma unroll
        for (int q = 0; q < 4; ++q) pre[q] = *(const float4*)(src + q * 4);
      } else {
        #pragma unroll
        for (int q = 0; q < 4; ++q) {
          int jb = j0 + scol + q * 4;
          pre[q].x = (jb + 0 < 50000) ? src[q*4 + 0] : 0.f;
          pre[q].y = (jb + 1 < 50000) ? src[q*4 + 1] : 0.f;
          pre[q].z = (jb + 2 < 50000) ? src[q*4 + 2] : 0.f;
          pre[q].w = (jb + 3 < 50000) ? src[q*4 + 3] : 0.f;
        }
      }
    }
    bf16x8 ahi[4], alo[4];
    #pragma unroll
    for (int im = 0; im < 4; ++im) {
      const u16* ha = hhl + (size_t)(im * 16 + ln) * 1024 + ks * 32 + lg * 8;
      ahi[im] = *(const bf16x8*)(ha);
      alo[im] = *(const bf16x8*)(ha + 65536);
    }
    bf16x8 bfr[2];
    #pragma unroll
    for (int nf = 0; nf < 2; ++nf) {
      u16x8 pv;
      #pragma unroll
      for (int i = 0; i < 8; ++i)
        pv[i] = f2bf(Bs[cur][(lg * 8 + i) * 136 + w * 32 + nf * 16 + ln]);
      bfr[nf] = *(bf16x8*)&pv;
    }
    #pragma unroll
    for (int im = 0; im < 4; ++im)
      #pragma unroll
      for (int nf = 0; nf < 2; ++nf) {
        acc[im][nf] = __builtin_amdgcn_mfma_f32_16x16x32_bf16(alo[im], bfr[nf], acc[im][nf], 0, 0, 0);
        acc[im][nf] = __builtin_amdgcn_mfma_f32_16x16x32_bf16(ahi[im], bfr[nf], acc[im][nf], 0, 0, 0);
      }
    if (ks < 31) {
      #pragma unroll
      for (int q = 0; q < 4; ++q)
        *(float4*)&Bs[cur ^ 1][srow * 136 + scol + q * 4] = pre[q];
    }
    __syncthreads();
  }

  #pragma unroll
  for (int nf = 0; nf < 2; ++nf) {
    int c = j0 + w * 32 + nf * 16 + ln;
    if (c < 50000) {
      float fb = fcb[c];
      #pragma unroll
      for (int im = 0; im < 4; ++im)
        #pragma unroll
        for (int r = 0; r < 4; ++r) {
          int row = im * 16 + lg * 4 + r;
          logits[(size_t)row * 50000 + c] = acc[im][nf][r] + fb;
        }
    }
  }
}

// ---------------- fallback f32 fc (used when ws too small for scratch arena)
__global__ void __launch_bounds__(256)
k_fc_f32(const float* __restrict__ dout_ro, const float* __restrict__ fcw,
         const float* __restrict__ fcb, float* __restrict__ logits) {
  __shared__ float ol[64][68];
  __shared__ float wl[64][132];
  const int t = threadIdx.x;
  const int j0 = blockIdx.x * 128;
  const int tb = t >> 5, tj = t & 31;
  const float* hf = dout_ro + 3200000u;
  const float* hb = dout_ro + 3200000u + 65536u;
  float acc[8][4];
  #pragma unroll
  for (int bi = 0; bi < 8; ++bi)
    #pragma unroll
    for (int ji = 0; ji < 4; ++ji) acc[bi][ji] = 0.f;

  for (int k0 = 0; k0 < 1024; k0 += 64) {
    __syncthreads();
    {
      int bb = t >> 2, kq = (t & 3) * 16;
      const float* src = (k0 < 512) ? (hf + (size_t)bb * 512 + k0 + kq)
                                    : (hb + (size_t)bb * 512 + (k0 - 512) + kq);
      #pragma unroll
      for (int i = 0; i < 4; ++i) {
        float4 v = *(const float4*)(src + i * 4);
        ol[kq + i*4 + 0][bb] = v.x;
        ol[kq + i*4 + 1][bb] = v.y;
        ol[kq + i*4 + 2][bb] = v.z;
        ol[kq + i*4 + 3][bb] = v.w;
      }
    }
    {
      int kk = t >> 2, jh = (t & 3) * 32;
      const float* wsrc = fcw + (size_t)(k0 + kk) * 50000 + j0 + jh;
      #pragma unroll
      for (int i = 0; i < 8; ++i) {
        int j = j0 + jh + i * 4;
        float4 v;
        if (j + 3 < 50000) {
          v = *(const float4*)(wsrc + i * 4);
        } else {
          v.x = (j + 0 < 50000) ? wsrc[i*4 + 0] : 0.f;
          v.y = (j + 1 < 50000) ? wsrc[i*4 + 1] : 0.f;
          v.z = (j + 2 < 50000) ? wsrc[i*4 + 2] : 0.f;
          v.w = 0.f;
        }
        *(float4*)&wl[kk][jh + i * 4] = v;
      }
    }
    __syncthreads();
    #pragma unroll 4
    for (int kk = 0; kk < 64; ++kk) {
      float4 wv = *(const float4*)&wl[kk][tj * 4];
      float4 q0 = *(const float4*)&ol[kk][tb * 8];
      float4 q1 = *(const float4*)&ol[kk][tb * 8 + 4];
      float obv[8] = {q0.x, q0.y, q0.z, q0.w, q1.x, q1.y, q1.z, q1.w};
      #pragma unroll
      for (int bi = 0; bi < 8; ++bi) {
        acc[bi][0] += obv[bi] * wv.x;
        acc[bi][1] += obv[bi] * wv.y;
        acc[bi][2] += obv[bi] * wv.z;
        acc[bi][3] += obv[bi] * wv.w;
      }
    }
  }

  const int j = j0 + tj * 4;
  if (j + 3 < 50000) {
    float4 fb = *(const float4*)(fcb + j);
    #pragma unroll
    for (int bi = 0; bi < 8; ++bi) {
      float4 r;
      r.x = acc[bi][0] + fb.x; r.y = acc[bi][1] + fb.y;
      r.z = acc[bi][2] + fb.z; r.w = acc[bi][3] + fb.w;
      *(float4*)&logits[(size_t)(tb * 8 + bi) * 50000 + j] = r;
    }
  } else {
    for (int ji = 0; ji < 4; ++ji) {
      if (j + ji < 50000) {
        float fb = fcb[j + ji];
        for (int bi = 0; bi < 8; ++bi)
          logits[(size_t)(tb * 8 + bi) * 50000 + j + ji] = acc[bi][ji] + fb;
      }
    }
  }
}

extern "C" void kernel_launch(void* const* d_in, const int* in_sizes, int n_in,
                              void* d_out, int out_size, void* d_ws, size_t ws_size,
                              hipStream_t stream) {
  const int*   x    = (const int*)  d_in[0];
  const float* cfwd = (const float*)d_in[1];
  const float* cbwd = (const float*)d_in[2];
  const float* enc  = (const float*)d_in[3];
  const float* emb  = (const float*)d_in[4];
  const float* W1w  = (const float*)d_in[5];
  const float* W1b  = (const float*)d_in[6];
  const float* W2w  = (const float*)d_in[7];
  const float* W2b  = (const float*)d_in[8];
  const float* W3w  = (const float*)d_in[9];
  const float* W3b  = (const float*)d_in[10];
  const float* Vw   = (const float*)d_in[11];
  const float* Vb   = (const float*)d_in[12];
  const float* Kf   = (const float*)d_in[13];
  const float* bfv  = (const float*)d_in[14];
  const float* Kb   = (const float*)d_in[15];
  const float* bbv  = (const float*)d_in[16];
  const float* fcw  = (const float*)d_in[17];
  const float* fcb  = (const float*)d_in[18];
  float* out = (float*)d_out;

  const bool haveWs = (ws_size >= SCRATCH_BYTES);
  float* S = haveWs ? (float*)d_ws : out;   // fallback carve ends 3065856 < 3200000
  u16*   w1p   = (u16*)S;
  float* hpb   = S + OF_HPB;
  float* ctxp  = S + OF_CTXP;
  float* stats = S + OF_STATS;
  float* xin   = S + OF_XIN;
  float* zpart = S + OF_ZPART;
  u16*   hhl   = (u16*)(S + OF_HHL);

  k_prep_w1<<<64, 256, 0, stream>>>(W1w, w1p);
  k_prep_hp<<<64, 256, 0, stream>>>(cfwd, cbwd, W2w, W2b, W3w, W3b, W1b, hpb);
  k_attn<<<2048, 1024, 0, stream>>>(enc, w1p, hpb, Vw, Vb, ctxp, stats);
  k_attn_reduce<<<64, 256, 0, stream>>>(ctxp, stats, x, emb, xin);
  k_lstm_gemm<<<256, 256, 0, stream>>>(xin, Kf, Kb, zpart);
  k_gates<<<128, 512, 0, stream>>>(zpart, bfv, bbv, out, hhl);
  if (haveWs) k_fc_mfma<<<392, 256, 0, stream>>>(fcw, hhl, fcb, out);
  else        k_fc_f32<<<391, 256, 0, stream>>>(out, fcw, fcb, out);
}

// Round 10
// 508.450 us; speedup vs baseline: 1.0812x; 1.0630x over previous
//
#include <hip/hip_runtime.h>

using u16 = unsigned short;
typedef float f32x4 __attribute__((ext_vector_type(4)));
typedef float f32x16 __attribute__((ext_vector_type(16)));
typedef __bf16 bf16x8 __attribute__((ext_vector_type(8)));
typedef u16 u16x8 __attribute__((ext_vector_type(8)));
typedef u16 u16x4 __attribute__((ext_vector_type(4)));

// dims: B=64, S=2048, ENC=1024, U=512, E=256, V=50000, IN=1280
// scratch layout (float units)
static constexpr int OF_HPB   = 262144;    // w1p: 512K u16 = 262144 floats
static constexpr int OF_CTXP  = 294912;    // hpb: 64*512
static constexpr int OF_STATS = 2392064;   // ctxp: 2048*1024
static constexpr int OF_XIN   = 2394112;   // stats: 2048
static constexpr int OF_ZPART = 2476032;   // xin: 64*1280
static constexpr int OF_HHL   = 3000320;   // zpart: 4*64*2048; hhl: 2*64*1024 u16
static constexpr size_t SCRATCH_FLOATS = 3065856;
static constexpr size_t SCRATCH_BYTES  = SCRATCH_FLOATS * 4ull;   // ~12.3 MB

__device__ __forceinline__ u16 f2bf(float f) {
  unsigned u = __float_as_uint(f);
  u += 0x7FFFu + ((u >> 16) & 1u);   // RNE; inputs finite
  return (u16)(u >> 16);
}
__device__ __forceinline__ float bf2f(u16 u) {
  return __uint_as_float((unsigned)u << 16);
}
__device__ __forceinline__ float fast_tanh(float x) {
  x = fminf(fmaxf(x, -20.f), 20.f);
  float e = __expf(2.f * x);
  return (e - 1.f) / (e + 1.f);
}
__device__ __forceinline__ float fast_sig(float x) { return 1.f / (1.f + __expf(-x)); }

// ---------------- W1 (1024x512 f32 [k][u]) -> bf16 packed for 32x32x16 B-frags:
// w1p[ks16*8192 + (wv*64 + l)*8 + e] = W1[ks16*16 + (l>>5)*8 + e][wv*32 + (l&31)]
__global__ void k_prep_w1(const float* __restrict__ W1w, u16* __restrict__ w1p) {
  __shared__ float tile[16][516];
  const int t = threadIdx.x;          // 256
  const int ks = blockIdx.x;          // 64
  {
    int kk = t >> 4, u0 = (t & 15) * 32;
    const float* src = W1w + (size_t)(ks * 16 + kk) * 512 + u0;
    #pragma unroll
    for (int i = 0; i < 8; ++i)
      *(float4*)&tile[kk][u0 + i * 4] = *(const float4*)(src + i * 4);
  }
  __syncthreads();
  #pragma unroll
  for (int q = 0; q < 4; ++q) {
    int c = t + q * 256;              // chunk 0..1023
    int wv = c >> 6, l = c & 63;
    int u = wv * 32 + (l & 31), koct = l >> 5;
    u16x8 p;
    #pragma unroll
    for (int e = 0; e < 8; ++e) p[e] = f2bf(tile[koct * 8 + e][u]);
    *(u16x8*)(w1p + (size_t)ks * 8192 + (size_t)c * 8) = p;
  }
}

// ---------------- hpb[b][u] = c_fwd@W2 + W2_b + c_bwd@W3 + W3_b + W1_b
__global__ void k_prep_hp(const float* __restrict__ cf, const float* __restrict__ cb,
                          const float* __restrict__ W2w, const float* __restrict__ W2b,
                          const float* __restrict__ W3w, const float* __restrict__ W3b,
                          const float* __restrict__ W1b, float* __restrict__ hpb) {
  __shared__ float cfl[512], cbl[512];
  const int b = blockIdx.x, t = threadIdx.x;
  cfl[t] = cf[(size_t)b * 512 + t];       cfl[t + 256] = cf[(size_t)b * 512 + t + 256];
  cbl[t] = cb[(size_t)b * 512 + t];       cbl[t + 256] = cb[(size_t)b * 512 + t + 256];
  __syncthreads();
  const int u1 = t, u2 = t + 256;
  float a1 = W2b[u1] + W3b[u1] + W1b[u1];
  float a2 = W2b[u2] + W3b[u2] + W1b[u2];
  for (int k = 0; k < 512; ++k) {
    float c1 = cfl[k], c2 = cbl[k];
    const float* r2 = W2w + (size_t)k * 512;
    const float* r3 = W3w + (size_t)k * 512;
    a1 += c1 * r2[u1] + c2 * r3[u1];
    a2 += c1 * r2[u2] + c2 * r3[u2];
  }
  hpb[(size_t)b * 512 + u1] = a1;
  hpb[(size_t)b * 512 + u2] = a2;
}

// ---------------- fused attention v5: score GEMM (32x32x16, macro-BK=64) ->
// exp/stats -> tail-PV. 2048 blocks = 64 b x 32 tiles. 1024 thr = 16 waves,
// 2 blocks/CU. 16 macro-iters, ONE lgkm-only s_barrier each (4 micro K-steps,
// 8 MFMA + 8 ds_read_b128 per wave between barriers). A: all 1024 threads load
// one float4/macro, reg-held 2 macros deep (~64KB/CU HBM in flight), written
// to +8-padded chunk layout (2-way write banks, conflict-free b128 reads).
// B: 4 frags/macro direct global->reg (w1p L2-hot).
__global__ void __launch_bounds__(1024, 8)
k_attn(const float* __restrict__ enc, const u16* __restrict__ w1p,
       const float* __restrict__ hpb, const float* __restrict__ Vw,
       const float* __restrict__ Vb, float* __restrict__ ctxp,
       float* __restrict__ stats) {
  __shared__ __align__(16) u16 smem[8448];   // A dbuf 2x4128 u16; epi: 4224 f32

  const int t = threadIdx.x;
  const int bid = blockIdx.x;
  const int b = bid >> 5, tile = bid & 31;
  const size_t row0 = (size_t)b * 2048 + (size_t)tile * 64;

  const int l = t & 63, wv = t >> 6;         // 16 waves

  // B fragment source: contiguous per (k-step, wave); k-step stride 8192 u16
  const u16* bbase = w1p + (size_t)wv * 512 + (size_t)l * 8;

  // A staging: thread t loads float4 of row sr, macro-col quad sq4 (coalesced:
  // 16 consecutive lanes = 64 consecutive floats)
  const int sr = t >> 4, sq4 = t & 15;
  const float* a_src = enc + (row0 + sr) * 1024 + sq4 * 4;          // + km*64
  const int sm = sq4 >> 2, skoct = (sq4 >> 1) & 1, ssq = sq4 & 1;
  const int a_dst = sm * 1032 + (sr >> 5) * 512 + ((sr & 31) + skoct * 32) * 8 + ssq * 4;

  f32x16 acc0, acc1;
  #pragma unroll
  for (int i = 0; i < 16; ++i) { acc0[i] = 0.f; acc1[i] = 0.f; }

  float4 pv0, pv1;
  {  // prologue: stage macro 0; macros 1,2 in flight
    float4 v = *(const float4*)(a_src);
    u16x4 w4;
    w4[0] = f2bf(v.x); w4[1] = f2bf(v.y); w4[2] = f2bf(v.z); w4[3] = f2bf(v.w);
    *(u16x4*)(smem + a_dst) = w4;
    pv0 = *(const float4*)(a_src + 64);
    pv1 = *(const float4*)(a_src + 128);
  }
  asm volatile("s_waitcnt lgkmcnt(0)" ::: "memory");
  __builtin_amdgcn_s_barrier();
  __builtin_amdgcn_sched_barrier(0);

  for (int km = 0; km < 16; ++km) {
    const int cur = km & 1;
    if (km < 15) {                 // stage A(km+1) (loaded 2 macros ago)
      u16x4 w4;
      w4[0] = f2bf(pv0.x); w4[1] = f2bf(pv0.y); w4[2] = f2bf(pv0.z); w4[3] = f2bf(pv0.w);
      *(u16x4*)(smem + (cur ^ 1) * 4128 + a_dst) = w4;
      pv0 = pv1;
      if (km < 13) pv1 = *(const float4*)(a_src + (km + 3) * 64);   // A(km+3)
    }
    bf16x8 bfr[4];
    #pragma unroll
    for (int m = 0; m < 4; ++m)
      bfr[m] = *(const bf16x8*)(bbase + (size_t)(km * 4 + m) * 8192);  // L2-hot
    const u16* Ac = smem + cur * 4128;
    #pragma unroll
    for (int m = 0; m < 4; ++m) {
      bf16x8 a0 = *(const bf16x8*)(Ac + m * 1032 + l * 8);         // rows 0..31
      bf16x8 a1 = *(const bf16x8*)(Ac + m * 1032 + 512 + l * 8);   // rows 32..63
      acc0 = __builtin_amdgcn_mfma_f32_32x32x16_bf16(a0, bfr[m], acc0, 0, 0, 0);
      acc1 = __builtin_amdgcn_mfma_f32_32x32x16_bf16(a1, bfr[m], acc1, 0, 0, 0);
    }
    // raw barrier: LDS visibility only (lgkmcnt); vmem stays in flight
    asm volatile("s_waitcnt lgkmcnt(0)" ::: "memory");
    __builtin_amdgcn_s_barrier();
    __builtin_amdgcn_sched_barrier(0);
  }

  // ---- epilogue (smem reused as f32): score -> exp -> stats
  float* fsm = (float*)smem;
  float* red = fsm;            // [64][17]
  float* scv = fsm + 1088;     // [64]
  float* pcv = fsm + 1152;     // [3072]

  const int ucol = (wv << 5) + (l & 31);
  const float vwv = Vw[ucol];
  const float hpv = hpb[(size_t)b * 512 + ucol];
  const int hi4 = (l >> 5) * 4;
  const bool writer = ((l & 31) == 0);
  // D mapping (32x32): col=lane&31 (u), row=(r&3)+8*(r>>2)+4*(lane>>5) (s)
  #pragma unroll
  for (int im = 0; im < 2; ++im) {
    #pragma unroll
    for (int r = 0; r < 16; ++r) {
      float s = vwv * fast_tanh((im ? acc1[r] : acc0[r]) + hpv);
      s += __shfl_xor(s, 1);
      s += __shfl_xor(s, 2);
      s += __shfl_xor(s, 4);
      s += __shfl_xor(s, 8);
      s += __shfl_xor(s, 16);
      if (writer) {
        int sl = im * 32 + (r & 3) + 8 * (r >> 2) + hi4;
        red[sl * 17 + wv] = s;
      }
    }
  }
  __syncthreads();
  if (t < 64) {
    float s = Vb[0];
    #pragma unroll
    for (int wq = 0; wq < 16; ++wq) s += red[t * 17 + wq];
    float e = __expf(s);   // |score| bounded (~||Vw||_1): f32-safe without max-sub
    scv[t] = e;
    float p = e;
    p += __shfl_xor(p, 1);  p += __shfl_xor(p, 2);  p += __shfl_xor(p, 4);
    p += __shfl_xor(p, 8);  p += __shfl_xor(p, 16); p += __shfl_xor(p, 32);
    if (t == 0) stats[bid] = p;
  }
  __syncthreads();

  // ---- tail-PV: unnormalized partial ctx from own (L3-hot) f32 enc tile
  {
    const int c4 = (t & 255) * 4;
    const int rq = t >> 8;                 // 0..3 -> rows rq*16..+16
    const float* ep = enc + (row0 + rq * 16) * 1024 + c4;
    float ax = 0.f, ay = 0.f, az = 0.f, aw2 = 0.f;
    #pragma unroll 4
    for (int r = 0; r < 16; ++r) {
      float4 v = *(const float4*)(ep + (size_t)r * 1024);
      float sc = scv[rq * 16 + r];
      ax += sc * v.x; ay += sc * v.y; az += sc * v.z; aw2 += sc * v.w;
    }
    if (rq) {
      float4 st = {ax, ay, az, aw2};
      *(float4*)&pcv[(rq - 1) * 1024 + c4] = st;
    }
    __syncthreads();
    if (rq == 0) {
      float4 p1 = *(const float4*)&pcv[c4];
      float4 p2 = *(const float4*)&pcv[1024 + c4];
      float4 p3 = *(const float4*)&pcv[2048 + c4];
      float4 o = {ax + p1.x + p2.x + p3.x, ay + p1.y + p2.y + p3.y,
                  az + p1.z + p2.z + p3.z, aw2 + p1.w + p2.w + p3.w};
      *(float4*)&ctxp[(size_t)bid * 1024 + c4] = o;
    }
  }
}

// ---------------- combine tile partials -> xin[:, :1024]; gather emb -> xin[:, 1024:]
__global__ void k_attn_reduce(const float* __restrict__ ctxp, const float* __restrict__ stats,
                              const int* __restrict__ x, const float* __restrict__ emb,
                              float* __restrict__ xin) {
  __shared__ float ps[32];
  __shared__ float invs;
  const int b = blockIdx.x, t = threadIdx.x;
  if (t < 32) ps[t] = stats[b * 32 + t];
  __syncthreads();
  if (t == 0) {
    float s = 0.f;
    #pragma unroll
    for (int i = 0; i < 32; ++i) s += ps[i];
    invs = 1.f / s;
  }
  __syncthreads();
  const float inv = invs;
  #pragma unroll
  for (int i = 0; i < 4; ++i) {
    int c = t + i * 256;
    float a = 0.f;
    for (int chv = 0; chv < 32; ++chv)
      a += ctxp[((size_t)b * 32 + chv) * 1024 + c];
    xin[(size_t)b * 1280 + c] = a * inv;
  }
  xin[(size_t)b * 1280 + 1024 + t] = emb[(size_t)x[b] * 256 + t];
}

// ---------------- z_part = xin @ K  (dir x ksplit x jtile), f32
__global__ void k_lstm_gemm(const float* __restrict__ xin, const float* __restrict__ Kf,
                            const float* __restrict__ Kb, float* __restrict__ zpart) {
  __shared__ float xl[32][68];   // [kk][b], padded
  const int t = threadIdx.x;
  const int bid = blockIdx.x;          // 2 dir * 64 jt * 2 ks = 256
  const int dir = bid >> 7;
  const int jt  = (bid >> 1) & 63;
  const int ks  = bid & 1;
  const float* K = dir ? Kb : Kf;
  const int j  = jt * 32 + (t & 31);
  const int tb = t >> 5;               // 8 groups of 8 b
  const int brow = t >> 2, kq = (t & 3) * 8;
  float acc[8] = {0,0,0,0,0,0,0,0};
  for (int k0 = ks * 640; k0 < ks * 640 + 640; k0 += 32) {
    float4 x0 = *(const float4*)&xin[(size_t)brow * 1280 + k0 + kq];
    float4 x1 = *(const float4*)&xin[(size_t)brow * 1280 + k0 + kq + 4];
    __syncthreads();
    xl[kq+0][brow]=x0.x; xl[kq+1][brow]=x0.y; xl[kq+2][brow]=x0.z; xl[kq+3][brow]=x0.w;
    xl[kq+4][brow]=x1.x; xl[kq+5][brow]=x1.y; xl[kq+6][brow]=x1.z; xl[kq+7][brow]=x1.w;
    __syncthreads();
    const float* Kp = K + (size_t)k0 * 2048 + j;
    #pragma unroll 8
    for (int kk = 0; kk < 32; ++kk) {
      float wv = Kp[(size_t)kk * 2048];
      float4 v0 = *(const float4*)&xl[kk][tb * 8];
      float4 v1 = *(const float4*)&xl[kk][tb * 8 + 4];
      acc[0] += v0.x * wv; acc[1] += v0.y * wv; acc[2] += v0.z * wv; acc[3] += v0.w * wv;
      acc[4] += v1.x * wv; acc[5] += v1.y * wv; acc[6] += v1.z * wv; acc[7] += v1.w * wv;
    }
  }
  float* zp = zpart + ((size_t)dir * 2 + ks) * 64 * 2048;
  #pragma unroll
  for (int i = 0; i < 8; ++i)
    zp[(size_t)(tb * 8 + i) * 2048 + j] = acc[i];
}

// ---------------- gates: c = sig(i)*tanh(g); h = sig(o)*tanh(c); also h -> hi/lo bf16
__global__ void k_gates(const float* __restrict__ zpart, const float* __restrict__ bfv,
                        const float* __restrict__ bbv, float* __restrict__ dout,
                        u16* __restrict__ hhl) {
  const int dir = blockIdx.x >> 6, b = blockIdx.x & 63, u = threadIdx.x;
  const float* bias = dir ? bbv : bfv;
  const float* z0 = zpart + ((size_t)dir * 2 + 0) * 131072 + (size_t)b * 2048;
  const float* z1 = zpart + ((size_t)dir * 2 + 1) * 131072 + (size_t)b * 2048;
  float zi = z0[u]        + z1[u]        + bias[u];
  float zg = z0[1024 + u] + z1[1024 + u] + bias[1024 + u];
  float zo = z0[1536 + u] + z1[1536 + u] + bias[1536 + u];
  float c = fast_sig(zi) * fast_tanh(zg);
  float h = fast_sig(zo) * fast_tanh(c);
  size_t base = 3200000u + (size_t)dir * 65536u;
  dout[base + (size_t)b * 512 + u] = h;
  dout[base + 32768u + (size_t)b * 512 + u] = c;
  u16 hi = f2bf(h);
  u16 lo = f2bf(h - bf2f(hi));
  hhl[(size_t)b * 1024 + dir * 512 + u] = hi;
  hhl[65536u + (size_t)b * 1024 + dir * 512 + u] = lo;
}

// ---------------- logits = [hf hb] @ fc_w + fc_b  via MFMA, fcw read DIRECTLY as f32
// 392 blocks x 128 cols, 256 thr / 4 waves (1M x 4N, wave 64x32). B: f32 tile ->
// LDS [32][136] -> transpose-read + cvt. A: h hi/lo bf16 from L2-hot hhl.
__global__ void __launch_bounds__(256)
k_fc_mfma(const float* __restrict__ fcw, const u16* __restrict__ hhl,
          const float* __restrict__ fcb, float* __restrict__ logits) {
  __shared__ float Bs[2][32 * 136];
  const int t = threadIdx.x;
  const int j0 = blockIdx.x * 128;
  const int l = t & 63, w = t >> 6;
  const int ln = l & 15, lg = l >> 4;
  const int srow = t >> 3, scol = (t & 7) * 16;
  const bool interior = (j0 + 128 <= 50000);

  f32x4 acc[4][2];
  #pragma unroll
  for (int im = 0; im < 4; ++im)
    #pragma unroll
    for (int nf = 0; nf < 2; ++nf) acc[im][nf] = f32x4{0.f, 0.f, 0.f, 0.f};

  float4 pre[4];
  {
    const float* src = fcw + (size_t)srow * 50000 + j0 + scol;
    if (interior) {
      #pragma unroll
      for (int q = 0; q < 4; ++q) pre[q] = *(const float4*)(src + q * 4);
    } else {
      #pragma unroll
      for (int q = 0; q < 4; ++q) {
        int jb = j0 + scol + q * 4;
        pre[q].x = (jb + 0 < 50000) ? src[q*4 + 0] : 0.f;
        pre[q].y = (jb + 1 < 50000) ? src[q*4 + 1] : 0.f;
        pre[q].z = (jb + 2 < 50000) ? src[q*4 + 2] : 0.f;
        pre[q].w = (jb + 3 < 50000) ? src[q*4 + 3] : 0.f;
      }
    }
    #pragma unroll
    for (int q = 0; q < 4; ++q)
      *(float4*)&Bs[0][srow * 136 + scol + q * 4] = pre[q];
  }
  __syncthreads();

  for (int ks = 0; ks < 32; ++ks) {
    const int cur = ks & 1;
    if (ks < 31) {
      const float* src = fcw + (size_t)(ks + 1) * 32 * 50000 + (size_t)srow * 50000 + j0 + scol;
      if (interior) {
        #pragma unroll
        for (int q = 0; q < 4; ++q) pre[q] = *(const float4*)(src + q * 4);
      } else {
        #pragma unroll
        for (int q = 0; q < 4; ++q) {
          int jb = j0 + scol + q * 4;
          pre[q].x = (jb + 0 < 50000) ? src[q*4 + 0] : 0.f;
          pre[q].y = (jb + 1 < 50000) ? src[q*4 + 1] : 0.f;
          pre[q].z = (jb + 2 < 50000) ? src[q*4 + 2] : 0.f;
          pre[q].w = (jb + 3 < 50000) ? src[q*4 + 3] : 0.f;
        }
      }
    }
    bf16x8 ahi[4], alo[4];
    #pragma unroll
    for (int im = 0; im < 4; ++im) {
      const u16* ha = hhl + (size_t)(im * 16 + ln) * 1024 + ks * 32 + lg * 8;
      ahi[im] = *(const bf16x8*)(ha);
      alo[im] = *(const bf16x8*)(ha + 65536);
    }
    bf16x8 bfr[2];
    #pragma unroll
    for (int nf = 0; nf < 2; ++nf) {
      u16x8 pv;
      #pragma unroll
      for (int i = 0; i < 8; ++i)
        pv[i] = f2bf(Bs[cur][(lg * 8 + i) * 136 + w * 32 + nf * 16 + ln]);
      bfr[nf] = *(bf16x8*)&pv;
    }
    #pragma unroll
    for (int im = 0; im < 4; ++im)
      #pragma unroll
      for (int nf = 0; nf < 2; ++nf) {
        acc[im][nf] = __builtin_amdgcn_mfma_f32_16x16x32_bf16(alo[im], bfr[nf], acc[im][nf], 0, 0, 0);
        acc[im][nf] = __builtin_amdgcn_mfma_f32_16x16x32_bf16(ahi[im], bfr[nf], acc[im][nf], 0, 0, 0);
      }
    if (ks < 31) {
      #pragma unroll
      for (int q = 0; q < 4; ++q)
        *(float4*)&Bs[cur ^ 1][srow * 136 + scol + q * 4] = pre[q];
    }
    __syncthreads();
  }

  #pragma unroll
  for (int nf = 0; nf < 2; ++nf) {
    int c = j0 + w * 32 + nf * 16 + ln;
    if (c < 50000) {
      float fb = fcb[c];
      #pragma unroll
      for (int im = 0; im < 4; ++im)
        #pragma unroll
        for (int r = 0; r < 4; ++r) {
          int row = im * 16 + lg * 4 + r;
          logits[(size_t)row * 50000 + c] = acc[im][nf][r] + fb;
        }
    }
  }
}

// ---------------- fallback f32 fc (used when ws too small for scratch arena)
__global__ void __launch_bounds__(256)
k_fc_f32(const float* __restrict__ dout_ro, const float* __restrict__ fcw,
         const float* __restrict__ fcb, float* __restrict__ logits) {
  __shared__ float ol[64][68];
  __shared__ float wl[64][132];
  const int t = threadIdx.x;
  const int j0 = blockIdx.x * 128;
  const int tb = t >> 5, tj = t & 31;
  const float* hf = dout_ro + 3200000u;
  const float* hb = dout_ro + 3200000u + 65536u;
  float acc[8][4];
  #pragma unroll
  for (int bi = 0; bi < 8; ++bi)
    #pragma unroll
    for (int ji = 0; ji < 4; ++ji) acc[bi][ji] = 0.f;

  for (int k0 = 0; k0 < 1024; k0 += 64) {
    __syncthreads();
    {
      int bb = t >> 2, kq = (t & 3) * 16;
      const float* src = (k0 < 512) ? (hf + (size_t)bb * 512 + k0 + kq)
                                    : (hb + (size_t)bb * 512 + (k0 - 512) + kq);
      #pragma unroll
      for (int i = 0; i < 4; ++i) {
        float4 v = *(const float4*)(src + i * 4);
        ol[kq + i*4 + 0][bb] = v.x;
        ol[kq + i*4 + 1][bb] = v.y;
        ol[kq + i*4 + 2][bb] = v.z;
        ol[kq + i*4 + 3][bb] = v.w;
      }
    }
    {
      int kk = t >> 2, jh = (t & 3) * 32;
      const float* wsrc = fcw + (size_t)(k0 + kk) * 50000 + j0 + jh;
      #pragma unroll
      for (int i = 0; i < 8; ++i) {
        int j = j0 + jh + i * 4;
        float4 v;
        if (j + 3 < 50000) {
          v = *(const float4*)(wsrc + i * 4);
        } else {
          v.x = (j + 0 < 50000) ? wsrc[i*4 + 0] : 0.f;
          v.y = (j + 1 < 50000) ? wsrc[i*4 + 1] : 0.f;
          v.z = (j + 2 < 50000) ? wsrc[i*4 + 2] : 0.f;
          v.w = 0.f;
        }
        *(float4*)&wl[kk][jh + i * 4] = v;
      }
    }
    __syncthreads();
    #pragma unroll 4
    for (int kk = 0; kk < 64; ++kk) {
      float4 wv = *(const float4*)&wl[kk][tj * 4];
      float4 q0 = *(const float4*)&ol[kk][tb * 8];
      float4 q1 = *(const float4*)&ol[kk][tb * 8 + 4];
      float obv[8] = {q0.x, q0.y, q0.z, q0.w, q1.x, q1.y, q1.z, q1.w};
      #pragma unroll
      for (int bi = 0; bi < 8; ++bi) {
        acc[bi][0] += obv[bi] * wv.x;
        acc[bi][1] += obv[bi] * wv.y;
        acc[bi][2] += obv[bi] * wv.z;
        acc[bi][3] += obv[bi] * wv.w;
      }
    }
  }

  const int j = j0 + tj * 4;
  if (j + 3 < 50000) {
    float4 fb = *(const float4*)(fcb + j);
    #pragma unroll
    for (int bi = 0; bi < 8; ++bi) {
      float4 r;
      r.x = acc[bi][0] + fb.x; r.y = acc[bi][1] + fb.y;
      r.z = acc[bi][2] + fb.z; r.w = acc[bi][3] + fb.w;
      *(float4*)&logits[(size_t)(tb * 8 + bi) * 50000 + j] = r;
    }
  } else {
    for (int ji = 0; ji < 4; ++ji) {
      if (j + ji < 50000) {
        float fb = fcb[j + ji];
        for (int bi = 0; bi < 8; ++bi)
          logits[(size_t)(tb * 8 + bi) * 50000 + j + ji] = acc[bi][ji] + fb;
      }
    }
  }
}

extern "C" void kernel_launch(void* const* d_in, const int* in_sizes, int n_in,
                              void* d_out, int out_size, void* d_ws, size_t ws_size,
                              hipStream_t stream) {
  const int*   x    = (const int*)  d_in[0];
  const float* cfwd = (const float*)d_in[1];
  const float* cbwd = (const float*)d_in[2];
  const float* enc  = (const float*)d_in[3];
  const float* emb  = (const float*)d_in[4];
  const float* W1w  = (const float*)d_in[5];
  const float* W1b  = (const float*)d_in[6];
  const float* W2w  = (const float*)d_in[7];
  const float* W2b  = (const float*)d_in[8];
  const float* W3w  = (const float*)d_in[9];
  const float* W3b  = (const float*)d_in[10];
  const float* Vw   = (const float*)d_in[11];
  const float* Vb   = (const float*)d_in[12];
  const float* Kf   = (const float*)d_in[13];
  const float* bfv  = (const float*)d_in[14];
  const float* Kb   = (const float*)d_in[15];
  const float* bbv  = (const float*)d_in[16];
  const float* fcw  = (const float*)d_in[17];
  const float* fcb  = (const float*)d_in[18];
  float* out = (float*)d_out;

  const bool haveWs = (ws_size >= SCRATCH_BYTES);
  float* S = haveWs ? (float*)d_ws : out;   // fallback carve ends 3065856 < 3200000
  u16*   w1p   = (u16*)S;
  float* hpb   = S + OF_HPB;
  float* ctxp  = S + OF_CTXP;
  float* stats = S + OF_STATS;
  float* xin   = S + OF_XIN;
  float* zpart = S + OF_ZPART;
  u16*   hhl   = (u16*)(S + OF_HHL);

  k_prep_w1<<<64, 256, 0, stream>>>(W1w, w1p);
  k_prep_hp<<<64, 256, 0, stream>>>(cfwd, cbwd, W2w, W2b, W3w, W3b, W1b, hpb);
  k_attn<<<2048, 1024, 0, stream>>>(enc, w1p, hpb, Vw, Vb, ctxp, stats);
  k_attn_reduce<<<64, 256, 0, stream>>>(ctxp, stats, x, emb, xin);
  k_lstm_gemm<<<256, 256, 0, stream>>>(xin, Kf, Kb, zpart);
  k_gates<<<128, 512, 0, stream>>>(zpart, bfv, bbv, out, hhl);
  if (haveWs) k_fc_mfma<<<392, 256, 0, stream>>>(fcw, hhl, fcb, out);
  else        k_fc_f32<<<391, 256, 0, stream>>>(out, fcw, fcb, out);
}